// Round 10
// baseline (325.256 us; speedup 1.0000x reference)
//
#include <hip/hip_runtime.h>

#define HIDDEN 16
#define N_FEAT 128
#define EMBED 128
#define N_GRAPHS 64
#define BSH 8              // 256 nodes per bucket
#define MAXB 512           // bucket slots (nbuck = 391 here)
#define ESL 8192           // edges per slice
#define NSMAX 256          // max slices (supports 2M edges)

typedef unsigned int uint;

// bf16x2 pack/unpack (round-to-nearest-even)
__device__ inline uint pk2(float a, float b) {
    uint ua = __float_as_uint(a), ub = __float_as_uint(b);
    ua = (ua + 0x7FFFu + ((ua >> 16) & 1u)) >> 16;
    ub = (ub + 0x7FFFu + ((ub >> 16) & 1u)) & 0xFFFF0000u;
    return ua | ub;
}
__device__ inline float2 upk2(uint w) {
    return make_float2(__uint_as_float(w << 16), __uint_as_float(w & 0xFFFF0000u));
}
__device__ inline int aload(const int* p) {
    return __hip_atomic_load(p, __ATOMIC_RELAXED, __HIP_MEMORY_SCOPE_AGENT);
}
__device__ inline float aloadf(const float* p) {
    return __hip_atomic_load(p, __ATOMIC_RELAXED, __HIP_MEMORY_SCOPE_AGENT);
}

// ---- K1: slice-local counting sort -> ebuf (linear, coalesced) + ptab[(b,s)]
// last block (ticket) scans ghist -> gbase
__global__ void __launch_bounds__(1024)
k_part2(const int* __restrict__ src, const int* __restrict__ dst,
        int n_edges, int nbuck,
        uint* __restrict__ ebuf, uint* __restrict__ ptab,
        int* __restrict__ ghist, int* __restrict__ gbase, int* __restrict__ ticket) {
    __shared__ int hcnt[MAXB], hincl[MAXB], hrank[MAXB];
    __shared__ uint stage[ESL];      // 32 KB
    __shared__ int amLast;
    int tid = threadIdx.x;
    for (int i = tid; i < MAXB; i += 1024) { hcnt[i] = 0; hrank[i] = 0; }
    __syncthreads();
    int base = blockIdx.x * ESL;
    int cnt = min(ESL, n_edges - base);
    int s_[8], d_[8];
#pragma unroll
    for (int j = 0; j < 8; j++) {
        int k = j * 1024 + tid;
        if (k < cnt) {
            s_[j] = src[base + k]; d_[j] = dst[base + k];
            atomicAdd(&hcnt[d_[j] >> BSH], 1);
        }
    }
    __syncthreads();
    if (tid < MAXB) hincl[tid] = hcnt[tid];
    __syncthreads();
    for (int st = 1; st < MAXB; st <<= 1) {
        int v = 0;
        if (tid < MAXB && tid >= st) v = hincl[tid - st];
        __syncthreads();
        if (tid < MAXB) hincl[tid] += v;
        __syncthreads();
    }
    if (tid < MAXB) {
        int c = hcnt[tid];
        ptab[(size_t)tid * NSMAX + blockIdx.x] = ((uint)(hincl[tid] - c) << 16) | (uint)c;
        if (c) atomicAdd(&ghist[tid], c);
    }
    __syncthreads();
#pragma unroll
    for (int j = 0; j < 8; j++) {
        int k = j * 1024 + tid;
        if (k < cnt) {
            int b = d_[j] >> BSH;
            int r = atomicAdd(&hrank[b], 1);
            stage[hincl[b] - hcnt[b] + r] = ((uint)s_[j] << 8) | ((uint)d_[j] & 255u);
        }
    }
    __syncthreads();
    for (int t = tid; t < cnt; t += 1024) ebuf[base + t] = stage[t];
    // last-block scan of ghist -> gbase
    __threadfence();
    __syncthreads();
    if (tid == 0) amLast = (atomicAdd(ticket, 1) == (int)gridDim.x - 1);
    __syncthreads();
    if (amLast) {
        int v = 0;
        if (tid < MAXB) { v = aload(&ghist[tid]); hcnt[tid] = v; hincl[tid] = v; }
        __syncthreads();
        for (int st = 1; st < MAXB; st <<= 1) {
            int u = 0;
            if (tid < MAXB && tid >= st) u = hincl[tid - st];
            __syncthreads();
            if (tid < MAXB) hincl[tid] += u;
            __syncthreads();
        }
        if (tid < MAXB) gbase[tid] = hincl[tid] - hcnt[tid];
    }
}

// ---- K2: per-bucket CSR finalize: gather chunks -> LDS, hist/scan/rank -> rowp/dinv/col
__global__ void __launch_bounds__(1024)
k_csr2(const uint* __restrict__ ebuf, const uint* __restrict__ ptab,
       const int* __restrict__ gbase, int nslice, int n,
       int* __restrict__ rowp, float* __restrict__ dinv, int* __restrict__ col) {
    __shared__ uint eL[ESL];        // 32 KB
    __shared__ int coff[NSMAX];
    __shared__ int nh[256], nincl[256], nrank[256];
    int b = blockIdx.x, tid = threadIdx.x, nb0 = b << BSH;
    int ccnt = 0;
    if (tid < nslice) ccnt = (int)(ptab[(size_t)b * NSMAX + tid] & 0xFFFFu);
    if (tid < NSMAX) coff[tid] = ccnt;
    __syncthreads();
    for (int st = 1; st < NSMAX; st <<= 1) {
        int v = 0;
        if (tid < NSMAX && tid >= st) v = coff[tid - st];
        __syncthreads();
        if (tid < NSMAX) coff[tid] += v;
        __syncthreads();
    }
    int total = coff[NSMAX - 1];
    if (total > ESL) total = ESL;   // statistically impossible; memory-safety clamp
    // wave-per-chunk gather into LDS
    int wv = tid >> 6, ln = tid & 63;
    for (int s = wv; s < nslice; s += 16) {
        uint pe = ptab[(size_t)b * NSMAX + s];
        int off = (int)(pe >> 16), c = (int)(pe & 0xFFFFu);
        int cbase = coff[s] - c;
        for (int i = ln; i < c && (cbase + i) < ESL; i += 64)
            eL[cbase + i] = ebuf[(size_t)s * ESL + off + i];
    }
    __syncthreads();
    if (tid < 256) { nh[tid] = 0; nrank[tid] = 0; }
    __syncthreads();
    for (int t = tid; t < total; t += 1024)
        atomicAdd(&nh[eL[t] & 255u], 1);
    __syncthreads();
    if (tid < 256) nincl[tid] = nh[tid];
    __syncthreads();
    for (int st = 1; st < 256; st <<= 1) {
        int v = 0;
        if (tid < 256 && tid >= st) v = nincl[tid - st];
        __syncthreads();
        if (tid < 256) nincl[tid] += v;
        __syncthreads();
    }
    int g0 = gbase[b];
    if (tid < 256) {
        int node = nb0 + tid;
        if (node < n) {
            rowp[node] = g0 + nincl[tid] - nh[tid];
            dinv[node] = rsqrtf((float)nh[tid] + 1.0f);
        }
        if (tid == 0) {
            int e = nb0 + 256; if (e > n) e = n;
            rowp[e] = g0 + total;   // duplicate boundary writes are consistent
        }
    }
    __syncthreads();
    for (int t = tid; t < total; t += 1024) {
        uint e = eL[t];
        int l2 = (int)(e & 255u);
        int r = atomicAdd(&nrank[l2], 1);
        col[g0 + (nincl[l2] - nh[l2]) + r] = (int)(e >> 8);
    }
}

// ---- K3: h = x @ W1 ; Hs2 = bf16(h * dinv)
__global__ void k_gemm1(const float* __restrict__ x, const float* __restrict__ W1,
                        const float* __restrict__ dinv, uint* __restrict__ Hs2, int n) {
    __shared__ float Ws[N_FEAT * HIDDEN];   // 8 KB
    int tid = threadIdx.x;
    {
        const float4* w4 = (const float4*)W1;
        float4* s4 = (float4*)Ws;
        s4[tid * 2]     = w4[tid * 2];
        s4[tid * 2 + 1] = w4[tid * 2 + 1];
    }
    __syncthreads();
    int i = blockIdx.x * blockDim.x + tid;
    if (i >= n) return;

    float acc[HIDDEN];
#pragma unroll
    for (int o = 0; o < HIDDEN; o++) acc[o] = 0.f;

    const float4* xr = (const float4*)(x + (size_t)i * N_FEAT);
#pragma unroll 8
    for (int k4 = 0; k4 < N_FEAT / 4; k4++) {
        float4 xv = xr[k4];
        const float* w0 = &Ws[(k4 * 4 + 0) * HIDDEN];
        const float* w1 = &Ws[(k4 * 4 + 1) * HIDDEN];
        const float* w2 = &Ws[(k4 * 4 + 2) * HIDDEN];
        const float* w3 = &Ws[(k4 * 4 + 3) * HIDDEN];
#pragma unroll
        for (int o = 0; o < HIDDEN; o++)
            acc[o] += xv.x * w0[o] + xv.y * w1[o] + xv.z * w2[o] + xv.w * w3[o];
    }
    float di = dinv[i];
    uint o8[8];
#pragma unroll
    for (int j = 0; j < 8; j++) o8[j] = pk2(acc[2 * j] * di, acc[2 * j + 1] * di);
    uint4* hp = (uint4*)(Hs2 + (size_t)i * 8);
    hp[0] = make_uint4(o8[0], o8[1], o8[2], o8[3]);
    hp[1] = make_uint4(o8[4], o8[5], o8[6], o8[7]);
}

// ---- K4: pull aggregation, bf16 tables, 4-deep col prefetch (deg<=32 fast path)
template <int LAYER>
__global__ void k_pull(const uint* __restrict__ V2, const int* __restrict__ rowp,
                       const int* __restrict__ col, const float* __restrict__ dinv,
                       const float* __restrict__ b1, uint* __restrict__ out2, int n) {
    int wid = (blockIdx.x * blockDim.x + threadIdx.x) >> 6;
    int lane = threadIdx.x & 63;
    if (wid >= n) return;
    int f  = lane & 7;    // uint slot (2 features)
    int es = lane >> 3;   // edge slot 0..7
    int start = rowp[wid];
    int dg = rowp[wid + 1] - start;
    float ax = 0.f, ay = 0.f;
    int c0 = -1, c1 = -1, c2 = -1, c3 = -1;
    if (es      < dg) c0 = col[start + es];
    if (es + 8  < dg) c1 = col[start + es + 8];
    if (es + 16 < dg) c2 = col[start + es + 16];
    if (es + 24 < dg) c3 = col[start + es + 24];
    if (c0 >= 0) { float2 v = upk2(V2[(size_t)c0 * 8 + f]); ax += v.x; ay += v.y; }
    if (c1 >= 0) { float2 v = upk2(V2[(size_t)c1 * 8 + f]); ax += v.x; ay += v.y; }
    if (c2 >= 0) { float2 v = upk2(V2[(size_t)c2 * 8 + f]); ax += v.x; ay += v.y; }
    if (c3 >= 0) { float2 v = upk2(V2[(size_t)c3 * 8 + f]); ax += v.x; ay += v.y; }
    for (int j = es + 32; j < dg; j += 8) {   // rare tail (deg > 32)
        int s = col[start + j];
        float2 v = upk2(V2[(size_t)s * 8 + f]);
        ax += v.x; ay += v.y;
    }
    ax += __shfl_xor(ax, 8, 64);  ay += __shfl_xor(ay, 8, 64);
    ax += __shfl_xor(ax, 16, 64); ay += __shfl_xor(ay, 16, 64);
    ax += __shfl_xor(ax, 32, 64); ay += __shfl_xor(ay, 32, 64);
    if (lane < 8) {
        float2 h = upk2(V2[(size_t)wid * 8 + f]);   // self-loop
        float tx = ax + h.x, ty = ay + h.y;
        float di = dinv[wid];
        if (LAYER == 1) {
            float qa = fmaxf(di * tx + b1[2 * f],     0.f) * di;
            float qb = fmaxf(di * ty + b1[2 * f + 1], 0.f) * di;
            out2[(size_t)wid * 8 + f] = pk2(qa, qb);
        } else {
            out2[(size_t)wid * 8 + f] = pk2(di * tx, di * ty);
        }
    }
}

// ---- K5: pooling + (last block) output GEMM
__global__ void k_pool(const uint* __restrict__ R2, const int* __restrict__ batch,
                       const float* __restrict__ W2, const float* __restrict__ b2,
                       float* __restrict__ S, float* __restrict__ cnt,
                       int* __restrict__ ticket, float* __restrict__ out, int n) {
    __shared__ float ls[8 * HIDDEN];
    __shared__ float lc[8];
    __shared__ float Ssh[N_GRAPHS * HIDDEN];
    __shared__ float csh[N_GRAPHS];
    __shared__ int amLast;
    int tid = threadIdx.x;
    if (tid < 8) lc[tid] = 0.f;
    if (tid < 8 * HIDDEN) ls[tid] = 0.f;
    __syncthreads();

    int i0 = blockIdx.x * 256;
    int g0 = batch[i0 < n ? i0 : (n - 1)];
    int i = i0 + tid;
    if (i < n) {
        int g = batch[i];
        float r[HIDDEN];
#pragma unroll
        for (int j = 0; j < 8; j++) {
            float2 v = upk2(R2[(size_t)i * 8 + j]);
            r[2 * j] = v.x; r[2 * j + 1] = v.y;
        }
        int off = g - g0;
        if (off >= 0 && off < 8) {
#pragma unroll
            for (int o = 0; o < HIDDEN; o++) atomicAdd(&ls[off * HIDDEN + o], r[o]);
            atomicAdd(&lc[off], 1.f);
        } else {
#pragma unroll
            for (int o = 0; o < HIDDEN; o++) atomicAdd(&S[(size_t)g * HIDDEN + o], r[o]);
            atomicAdd(&cnt[g], 1.f);
        }
    }
    __syncthreads();
    if (tid < 8 * HIDDEN) {
        int bb = tid >> 4, o = tid & 15;
        int g = g0 + bb;
        float v = ls[bb * HIDDEN + o];
        if (v != 0.f && g < N_GRAPHS) atomicAdd(&S[(size_t)g * HIDDEN + o], v);
    }
    if (tid < 8) {
        int g = g0 + tid;
        float c = lc[tid];
        if (c != 0.f && g < N_GRAPHS) atomicAdd(&cnt[g], c);
    }
    // last block computes the 64x128 output GEMM
    __threadfence();
    __syncthreads();
    if (tid == 0) amLast = (atomicAdd(ticket, 1) == (int)gridDim.x - 1);
    __syncthreads();
    if (amLast) {
        for (int k = tid; k < N_GRAPHS * HIDDEN; k += 256) Ssh[k] = aloadf(&S[k]);
        for (int k = tid; k < N_GRAPHS; k += 256) csh[k] = aloadf(&cnt[k]);
        __syncthreads();
        for (int idx = tid; idx < N_GRAPHS * EMBED; idx += 256) {
            int g = idx >> 7, e = idx & 127;
            float c = csh[g];
            float acc = 0.f;
#pragma unroll
            for (int k = 0; k < HIDDEN; k++) acc += Ssh[g * HIDDEN + k] * W2[k * EMBED + e];
            out[idx] = (c > 0.f) ? (acc / c + b2[e]) : 0.f;
        }
    }
}

extern "C" void kernel_launch(void* const* d_in, const int* in_sizes, int n_in,
                              void* d_out, int out_size, void* d_ws, size_t ws_size,
                              hipStream_t stream) {
    const float* x     = (const float*)d_in[0];
    const int*   ei    = (const int*)  d_in[1];
    const int*   batch = (const int*)  d_in[2];
    const float* W1    = (const float*)d_in[3];
    const float* b1    = (const float*)d_in[4];
    const float* W2    = (const float*)d_in[5];
    const float* b2    = (const float*)d_in[6];
    float* out = (float*)d_out;

    const int n       = in_sizes[2];
    const int n_edges = in_sizes[1] / 2;
    const int* srcp = ei;
    const int* dstp = ei + n_edges;
    const int nbuck  = (n + 255) >> BSH;               // 391
    const int nslice = (n_edges + ESL - 1) / ESL;      // 196

    // workspace layout
    uint*  Hs2   = (uint*)d_ws;                    // n*8
    uint*  Q2    = Hs2 + (size_t)n * 8;            // n*8
    float* dinv  = (float*)(Q2 + (size_t)n * 8);   // n
    int*   rowp  = (int*)(dinv + n);               // n+2
    int*   col   = rowp + (n + 2);                 // n_edges
    uint*  ebuf  = (uint*)(col + n_edges);         // n_edges
    uint*  ptab  = ebuf + n_edges;                 // MAXB*NSMAX (512 KB)
    int*   ghist = (int*)(ptab + (size_t)MAXB * NSMAX);  // 512  -- memset from here
    int*   gbase = ghist + MAXB;                   // 512
    float* S     = (float*)(gbase + MAXB);         // 1024
    float* cnt   = S + N_GRAPHS * HIDDEN;          // 64
    int*   tks   = (int*)(cnt + N_GRAPHS);         // 4    -- memset to here
    uint*  R2    = ebuf;                           // n*8 <= n_edges, reuse after csr2

    hipMemsetAsync(ghist, 0,
                   (MAXB + MAXB + N_GRAPHS * HIDDEN + N_GRAPHS + 4) * sizeof(int), stream);

    k_part2<<<nslice, 1024, 0, stream>>>(srcp, dstp, n_edges, nbuck,
                                         ebuf, ptab, ghist, gbase, tks);
    k_csr2 <<<nbuck, 1024, 0, stream>>>(ebuf, ptab, gbase, nslice, n, rowp, dinv, col);

    const int nb = (n + 255) / 256;
    k_gemm1<<<nb, 256, 0, stream>>>(x, W1, dinv, Hs2, n);

    const int pullb = (n * 64 + 255) / 256;
    k_pull<1><<<pullb, 256, 0, stream>>>(Hs2, rowp, col, dinv, b1, Q2, n);
    k_pull<2><<<pullb, 256, 0, stream>>>(Q2,  rowp, col, dinv, b1, R2, n);

    k_pool <<<nb, 256, 0, stream>>>(R2, batch, W2, b2, S, cnt, tks + 1, out, n);
}

// Round 11
// 230.982 us; speedup vs baseline: 1.4081x; 1.4081x over previous
//
#include <hip/hip_runtime.h>

#define HIDDEN 16
#define N_FEAT 128
#define EMBED 128
#define N_GRAPHS 64
#define BSH 8              // 256 nodes per bucket
#define MAXB 512           // LDS bound on bucket count (nbuck = 391 here)
#define EPT 8              // edges per thread in hist/part (8192-edge slices)

typedef unsigned int uint;

// bf16x2 pack/unpack (round-to-nearest-even)
__device__ inline uint pk2(float a, float b) {
    uint ua = __float_as_uint(a), ub = __float_as_uint(b);
    ua = (ua + 0x7FFFu + ((ua >> 16) & 1u)) >> 16;
    ub = (ub + 0x7FFFu + ((ub >> 16) & 1u)) & 0xFFFF0000u;
    return ua | ub;
}
__device__ inline float2 upk2(uint w) {
    return make_float2(__uint_as_float(w << 16), __uint_as_float(w & 0xFFFF0000u));
}

// ---- K1: global bucket histogram of dst>>BSH (8192-edge slices)
__global__ void __launch_bounds__(1024)
k_hist(const int* __restrict__ dst, int n_edges, int nbuck, int* __restrict__ ghist) {
    __shared__ int h[MAXB];
    for (int i = threadIdx.x; i < MAXB; i += 1024) h[i] = 0;
    __syncthreads();
    int base = blockIdx.x * (EPT * 1024);
#pragma unroll
    for (int j = 0; j < EPT; j++) {
        int e = base + j * 1024 + threadIdx.x;
        if (e < n_edges) atomicAdd(&h[dst[e] >> BSH], 1);
    }
    __syncthreads();
    for (int b = threadIdx.x; b < nbuck; b += 1024)
        if (h[b]) atomicAdd(&ghist[b], h[b]);
}

// ---- K2: exclusive scan of bucket counts -> gbase; init reservation counters
__global__ void k_scan(const int* __restrict__ ghist, int nbuck,
                       int* __restrict__ gbase, int* __restrict__ gfill) {
    __shared__ int s[MAXB];
    int t = threadIdx.x;                       // 512 threads
    s[t] = (t < nbuck) ? ghist[t] : 0;
    __syncthreads();
    for (int st = 1; st < MAXB; st <<= 1) {
        int v = (t >= st) ? s[t - st] : 0;
        __syncthreads();
        s[t] += v;
        __syncthreads();
    }
    if (t < nbuck) {
        int excl = s[t] - ghist[t];
        gbase[t] = excl;
        gfill[t] = excl;
    }
}

// ---- K3: partition edges into bucket-contiguous packed ebuf (src<<8 | dst&255)
__global__ void __launch_bounds__(1024)
k_part(const int* __restrict__ src, const int* __restrict__ dst,
       int n_edges, int nbuck, int* __restrict__ gfill, uint* __restrict__ ebuf) {
    __shared__ int hcnt[MAXB];
    __shared__ int hincl[MAXB];   // inclusive scan; excl = hincl-hcnt
    __shared__ int hrank[MAXB];
    __shared__ int hbase[MAXB];
    __shared__ uint stage[EPT * 1024];            // 32 KB
    __shared__ unsigned short sbuck[EPT * 1024];  // 16 KB
    int tid = threadIdx.x;
    for (int i = tid; i < MAXB; i += 1024) { hcnt[i] = 0; hrank[i] = 0; }
    __syncthreads();
    int base = blockIdx.x * (EPT * 1024);
    int cnt = min(EPT * 1024, n_edges - base);
    int s_[EPT], d_[EPT];
#pragma unroll
    for (int j = 0; j < EPT; j++) {
        int k = j * 1024 + tid;
        if (k < cnt) {
            s_[j] = src[base + k]; d_[j] = dst[base + k];
            atomicAdd(&hcnt[d_[j] >> BSH], 1);
        }
    }
    __syncthreads();
    if (tid < MAXB) hincl[tid] = hcnt[tid];
    __syncthreads();
    for (int st = 1; st < MAXB; st <<= 1) {
        int v = 0;
        if (tid < MAXB && tid >= st) v = hincl[tid - st];
        __syncthreads();
        if (tid < MAXB) hincl[tid] += v;
        __syncthreads();
    }
    if (tid < nbuck && hcnt[tid] > 0)
        hbase[tid] = atomicAdd(&gfill[tid], hcnt[tid]);
    __syncthreads();
#pragma unroll
    for (int j = 0; j < EPT; j++) {
        int k = j * 1024 + tid;
        if (k < cnt) {
            int b = d_[j] >> BSH;
            int r = atomicAdd(&hrank[b], 1);
            int pos = hincl[b] - hcnt[b] + r;
            stage[pos] = ((uint)s_[j] << 8) | ((uint)d_[j] & 255u);
            sbuck[pos] = (unsigned short)b;
        }
    }
    __syncthreads();
    for (int t = tid; t < cnt; t += 1024) {
        int b = sbuck[t];
        ebuf[hbase[b] + (t - (hincl[b] - hcnt[b]))] = stage[t];
    }
}

// ---- K4: per-bucket CSR finalize from packed ebuf: deg, rowptr, col
__global__ void __launch_bounds__(1024)
k_csr(const uint* __restrict__ ebuf, const int* __restrict__ gbase,
      const int* __restrict__ ghist, int n,
      int* __restrict__ deg, int* __restrict__ rowp, int* __restrict__ col) {
    __shared__ int nh[256], nincl[256], nrank[256];
    int b = blockIdx.x;
    int tid = threadIdx.x;
    int seg0 = gbase[b];
    int cnt = ghist[b];
    int nb0 = b << BSH;
    if (tid < 256) { nh[tid] = 0; nrank[tid] = 0; }
    __syncthreads();
    for (int t = tid; t < cnt; t += 1024)
        atomicAdd(&nh[ebuf[seg0 + t] & 255u], 1);
    __syncthreads();
    if (tid < 256) nincl[tid] = nh[tid];
    __syncthreads();
    for (int st = 1; st < 256; st <<= 1) {
        int v = 0;
        if (tid < 256 && tid >= st) v = nincl[tid - st];
        __syncthreads();
        if (tid < 256) nincl[tid] += v;
        __syncthreads();
    }
    if (tid < 256) {
        int node = nb0 + tid;
        if (node < n) {
            deg[node]  = nh[tid];
            rowp[node] = seg0 + nincl[tid] - nh[tid];
        }
    }
    __syncthreads();
    for (int t = tid; t < cnt; t += 1024) {
        uint e = ebuf[seg0 + t];
        int ln = (int)(e & 255u);
        int r = atomicAdd(&nrank[ln], 1);
        col[seg0 + (nincl[ln] - nh[ln]) + r] = (int)(e >> 8);
    }
}

// ---- K5: h = x @ W1 ; dinv = rsqrt(deg+1) ; Hs2 = bf16(h * dinv)
__global__ void k_gemm1(const float* __restrict__ x, const float* __restrict__ W1,
                        const int* __restrict__ deg, float* __restrict__ dinv,
                        uint* __restrict__ Hs2, int n) {
    __shared__ float Ws[N_FEAT * HIDDEN];   // 8 KB
    int tid = threadIdx.x;
    {
        const float4* w4 = (const float4*)W1;
        float4* s4 = (float4*)Ws;
        s4[tid * 2]     = w4[tid * 2];
        s4[tid * 2 + 1] = w4[tid * 2 + 1];
    }
    __syncthreads();
    int i = blockIdx.x * blockDim.x + tid;
    if (i >= n) return;

    float acc[HIDDEN];
#pragma unroll
    for (int o = 0; o < HIDDEN; o++) acc[o] = 0.f;

    const float4* xr = (const float4*)(x + (size_t)i * N_FEAT);
#pragma unroll 8
    for (int k4 = 0; k4 < N_FEAT / 4; k4++) {
        float4 xv = xr[k4];
        const float* w0 = &Ws[(k4 * 4 + 0) * HIDDEN];
        const float* w1 = &Ws[(k4 * 4 + 1) * HIDDEN];
        const float* w2 = &Ws[(k4 * 4 + 2) * HIDDEN];
        const float* w3 = &Ws[(k4 * 4 + 3) * HIDDEN];
#pragma unroll
        for (int o = 0; o < HIDDEN; o++)
            acc[o] += xv.x * w0[o] + xv.y * w1[o] + xv.z * w2[o] + xv.w * w3[o];
    }
    float di = rsqrtf((float)deg[i] + 1.0f);
    dinv[i] = di;
    uint o8[8];
#pragma unroll
    for (int j = 0; j < 8; j++) o8[j] = pk2(acc[2 * j] * di, acc[2 * j + 1] * di);
    uint4* hp = (uint4*)(Hs2 + (size_t)i * 8);
    hp[0] = make_uint4(o8[0], o8[1], o8[2], o8[3]);
    hp[1] = make_uint4(o8[4], o8[5], o8[6], o8[7]);
}

// ---- K6: pull aggregation, bf16 tables; 4-deep predicated col prefetch (deg<=32 fast)
// LAYER 1: out2 = bf16( relu(dinv*(sum+self) + b1) * dinv )
// LAYER 2: out2 = bf16( dinv*(sum+self) )
template <int LAYER>
__global__ void k_pull(const uint* __restrict__ V2, const int* __restrict__ rowptr,
                       const int* __restrict__ deg, const int* __restrict__ col,
                       const float* __restrict__ dinv, const float* __restrict__ b1,
                       uint* __restrict__ out2, int n) {
    int wid = (blockIdx.x * blockDim.x + threadIdx.x) >> 6;
    int lane = threadIdx.x & 63;
    if (wid >= n) return;
    int f  = lane & 7;    // uint slot (2 features)
    int es = lane >> 3;   // edge slot 0..7
    int start = rowptr[wid];
    int dg = deg[wid];
    float ax = 0.f, ay = 0.f;
    int c0 = -1, c1 = -1, c2 = -1, c3 = -1;
    if (es      < dg) c0 = col[start + es];
    if (es + 8  < dg) c1 = col[start + es + 8];
    if (es + 16 < dg) c2 = col[start + es + 16];
    if (es + 24 < dg) c3 = col[start + es + 24];
    if (c0 >= 0) { float2 v = upk2(V2[(size_t)c0 * 8 + f]); ax += v.x; ay += v.y; }
    if (c1 >= 0) { float2 v = upk2(V2[(size_t)c1 * 8 + f]); ax += v.x; ay += v.y; }
    if (c2 >= 0) { float2 v = upk2(V2[(size_t)c2 * 8 + f]); ax += v.x; ay += v.y; }
    if (c3 >= 0) { float2 v = upk2(V2[(size_t)c3 * 8 + f]); ax += v.x; ay += v.y; }
    for (int j = es + 32; j < dg; j += 8) {   // rare tail (deg > 32)
        int s = col[start + j];
        float2 v = upk2(V2[(size_t)s * 8 + f]);
        ax += v.x; ay += v.y;
    }
    ax += __shfl_xor(ax, 8, 64);  ay += __shfl_xor(ay, 8, 64);
    ax += __shfl_xor(ax, 16, 64); ay += __shfl_xor(ay, 16, 64);
    ax += __shfl_xor(ax, 32, 64); ay += __shfl_xor(ay, 32, 64);
    if (lane < 8) {
        float2 h = upk2(V2[(size_t)wid * 8 + f]);   // self-loop
        float tx = ax + h.x, ty = ay + h.y;
        float di = dinv[wid];
        if (LAYER == 1) {
            float qa = fmaxf(di * tx + b1[2 * f],     0.f) * di;
            float qb = fmaxf(di * ty + b1[2 * f + 1], 0.f) * di;
            out2[(size_t)wid * 8 + f] = pk2(qa, qb);
        } else {
            out2[(size_t)wid * 8 + f] = pk2(di * tx, di * ty);
        }
    }
}

// ---- K7: pooling from bf16 R: S[batch] += R; cnt[batch] += 1 (sorted batch)
__global__ void k_pool(const uint* __restrict__ R2, const int* __restrict__ batch,
                       float* __restrict__ S, float* __restrict__ cnt, int n) {
    __shared__ float ls[8 * HIDDEN];
    __shared__ float lc[8];
    int tid = threadIdx.x;
    if (tid < 8) lc[tid] = 0.f;
    if (tid < 8 * HIDDEN) ls[tid] = 0.f;
    __syncthreads();

    int i0 = blockIdx.x * 256;
    int g0 = batch[i0 < n ? i0 : (n - 1)];
    int i = i0 + tid;
    if (i < n) {
        int g = batch[i];
        float r[HIDDEN];
#pragma unroll
        for (int j = 0; j < 8; j++) {
            float2 v = upk2(R2[(size_t)i * 8 + j]);
            r[2 * j] = v.x; r[2 * j + 1] = v.y;
        }
        int off = g - g0;
        if (off >= 0 && off < 8) {
#pragma unroll
            for (int o = 0; o < HIDDEN; o++) atomicAdd(&ls[off * HIDDEN + o], r[o]);
            atomicAdd(&lc[off], 1.f);
        } else {
#pragma unroll
            for (int o = 0; o < HIDDEN; o++) atomicAdd(&S[(size_t)g * HIDDEN + o], r[o]);
            atomicAdd(&cnt[g], 1.f);
        }
    }
    __syncthreads();
    if (tid < 8 * HIDDEN) {
        int b = tid >> 4, o = tid & 15;
        int g = g0 + b;
        float v = ls[b * HIDDEN + o];
        if (v != 0.f && g < N_GRAPHS) atomicAdd(&S[(size_t)g * HIDDEN + o], v);
    }
    if (tid < 8) {
        int g = g0 + tid;
        float c = lc[tid];
        if (c != 0.f && g < N_GRAPHS) atomicAdd(&cnt[g], c);
    }
}

// ---- K8: out[g][e] = (S[g]/cnt[g]) @ W2 + b2
__global__ void k_out(const float* __restrict__ S, const float* __restrict__ cnt,
                      const float* __restrict__ W2, const float* __restrict__ b2,
                      float* __restrict__ out) {
    int g = blockIdx.x;
    int e = threadIdx.x;
    float c = cnt[g];
    float acc = 0.f;
#pragma unroll
    for (int k = 0; k < HIDDEN; k++) acc += S[g * HIDDEN + k] * W2[k * EMBED + e];
    out[g * EMBED + e] = (c > 0.f) ? (acc / c + b2[e]) : 0.f;
}

extern "C" void kernel_launch(void* const* d_in, const int* in_sizes, int n_in,
                              void* d_out, int out_size, void* d_ws, size_t ws_size,
                              hipStream_t stream) {
    const float* x     = (const float*)d_in[0];
    const int*   ei    = (const int*)  d_in[1];
    const int*   batch = (const int*)  d_in[2];
    const float* W1    = (const float*)d_in[3];
    const float* b1    = (const float*)d_in[4];
    const float* W2    = (const float*)d_in[5];
    const float* b2    = (const float*)d_in[6];
    float* out = (float*)d_out;

    const int n       = in_sizes[2];
    const int n_edges = in_sizes[1] / 2;
    const int* srcp = ei;
    const int* dstp = ei + n_edges;
    const int nbuck = (n + 255) >> BSH;      // 391

    // workspace layout
    uint*  Hs2   = (uint*)d_ws;                  // n*8 uints (bf16x2)
    uint*  Q2    = Hs2 + (size_t)n * 8;          // n*8 uints
    float* dinv  = (float*)(Q2 + (size_t)n * 8); // n
    int*   deg   = (int*)(dinv + n);             // n
    int*   rowp  = deg + n;                      // n
    int*   col   = rowp + n;                     // n_edges
    uint*  ebuf  = (uint*)(col + n_edges);       // n_edges (R2 overlays after csr)
    int*   ghist = (int*)(ebuf + n_edges);       // MAXB   -- memset block starts here
    float* S     = (float*)(ghist + MAXB);       // 64*16
    float* cnt   = S + N_GRAPHS * HIDDEN;        // 64     -- memset block ends here
    int*   gbase = (int*)(cnt + N_GRAPHS);       // MAXB
    int*   gfill = gbase + MAXB;                 // MAXB
    uint*  R2    = ebuf;                         // n*8 uints <= n_edges uints

    // one memset covers ghist + S + cnt (contiguous)
    hipMemsetAsync(ghist, 0, (MAXB + N_GRAPHS * HIDDEN + N_GRAPHS) * sizeof(int), stream);

    const int pb8k = (n_edges + EPT * 1024 - 1) / (EPT * 1024);   // 196
    k_hist <<<pb8k, 1024, 0, stream>>>(dstp, n_edges, nbuck, ghist);
    k_scan <<<1, MAXB, 0, stream>>>(ghist, nbuck, gbase, gfill);
    k_part <<<pb8k, 1024, 0, stream>>>(srcp, dstp, n_edges, nbuck, gfill, ebuf);
    k_csr  <<<nbuck, 1024, 0, stream>>>(ebuf, gbase, ghist, n, deg, rowp, col);

    const int nb = (n + 255) / 256;
    k_gemm1<<<nb, 256, 0, stream>>>(x, W1, deg, dinv, Hs2, n);

    const int pullb = (n * 64 + 255) / 256;
    k_pull<1><<<pullb, 256, 0, stream>>>(Hs2, rowp, deg, col, dinv, b1, Q2, n);
    k_pull<2><<<pullb, 256, 0, stream>>>(Q2,  rowp, deg, col, dinv, b1, R2, n);

    k_pool <<<nb, 256, 0, stream>>>(R2, batch, S, cnt, n);
    k_out  <<<N_GRAPHS, EMBED, 0, stream>>>(S, cnt, W2, b2, out);
}